// Round 1
// baseline (231.596 us; speedup 1.0000x reference)
//
#include <hip/hip_runtime.h>
#include <math.h>

// Problem constants (from reference setup_inputs): B=2, S=1024, D=128
#define BB 2
#define SS 1024
#define DD 128

// ---------------------------------------------------------------------------
// Kernel A: fused QKV projection.
//   Q = sigmoid(x @ Wq^T + bq), K = sigmoid(x @ Wk^T + bk), V = x @ Wv^T + bv
// One block per (b,s) row; 128 threads; thread t computes output feature t
// for all three projections. x row staged in LDS (broadcast reads).
// ---------------------------------------------------------------------------
__global__ __launch_bounds__(DD) void qkv_kernel(
    const float* __restrict__ x,
    const float* __restrict__ Wq, const float* __restrict__ bq,
    const float* __restrict__ Wk, const float* __restrict__ bk,
    const float* __restrict__ Wv, const float* __restrict__ bv,
    float* __restrict__ Qo, float* __restrict__ Ko, float* __restrict__ Vo)
{
    __shared__ float xs[DD];
    const int row = blockIdx.x;      // b*SS + s
    const int t = threadIdx.x;       // output feature e

    xs[t] = x[row * DD + t];
    __syncthreads();

    const float4* wq4 = (const float4*)(Wq + t * DD);
    const float4* wk4 = (const float4*)(Wk + t * DD);
    const float4* wv4 = (const float4*)(Wv + t * DD);

    float aq = 0.f, ak = 0.f, av = 0.f;
    #pragma unroll 8
    for (int d4 = 0; d4 < DD / 4; ++d4) {
        const float x0 = xs[4 * d4 + 0];
        const float x1 = xs[4 * d4 + 1];
        const float x2 = xs[4 * d4 + 2];
        const float x3 = xs[4 * d4 + 3];
        float4 wq = wq4[d4];
        float4 wk = wk4[d4];
        float4 wv = wv4[d4];
        aq += wq.x * x0 + wq.y * x1 + wq.z * x2 + wq.w * x3;
        ak += wk.x * x0 + wk.y * x1 + wk.z * x2 + wk.w * x3;
        av += wv.x * x0 + wv.y * x1 + wv.z * x2 + wv.w * x3;
    }
    aq += bq[t];
    ak += bk[t];
    av += bv[t];

    Qo[row * DD + t] = 1.f / (1.f + __expf(-aq));   // sigmoid
    Ko[row * DD + t] = 1.f / (1.f + __expf(-ak));
    Vo[row * DD + t] = av;
}

// ---------------------------------------------------------------------------
// Kernel B: per-(b,q) row: Lukasiewicz scores + masked-to-0 softmax + PV.
//   truth[k] = 1 - (1/D) * sum_d relu(Q[q,d] - K[k,d])      (k <= q if causal)
//   masked entries get truth 0.0 (NOT -inf) and participate in softmax.
//   out[d]   = sum_k softmax(truth*10)[k] * V[k,d]
// 256 threads per block.
// ---------------------------------------------------------------------------
__global__ __launch_bounds__(256) void attn_kernel(
    const float* __restrict__ Q, const float* __restrict__ K,
    const float* __restrict__ V, const int* __restrict__ causal_flag,
    float* __restrict__ out)
{
    __shared__ float qs[DD];
    __shared__ float sc[SS];          // scores -> exp weights
    __shared__ float red[256];        // block reduction scratch
    __shared__ float pvs[8][DD];      // PV partials

    const int rowid = blockIdx.x;     // b*SS + q
    const int b = rowid >> 10;        // SS = 1024
    const int q = rowid & (SS - 1);
    const int t = threadIdx.x;
    const bool causal = (causal_flag[0] != 0);

    if (t < DD) qs[t] = Q[rowid * DD + t];
    __syncthreads();

    const float* Kb = K + b * SS * DD;
    const float* Vb = V + b * SS * DD;

    // ---- scores: each thread handles 4 k values ----
    for (int kk = t; kk < SS; kk += 256) {
        float s;
        if (causal && kk > q) {
            s = 0.f;                                  // masked -> truth 0.0
        } else {
            float acc = 0.f;
            const float4* k4 = (const float4*)(Kb + kk * DD);
            #pragma unroll 8
            for (int d4 = 0; d4 < DD / 4; ++d4) {
                float4 kv = k4[d4];
                acc += fmaxf(qs[4 * d4 + 0] - kv.x, 0.f)
                     + fmaxf(qs[4 * d4 + 1] - kv.y, 0.f)
                     + fmaxf(qs[4 * d4 + 2] - kv.z, 0.f)
                     + fmaxf(qs[4 * d4 + 3] - kv.w, 0.f);
            }
            s = 1.f - acc * (1.f / (float)DD);
        }
        sc[kk] = s * 10.f;                            // pre-scale for softmax
    }
    __syncthreads();

    // ---- softmax max-reduce over 1024 entries ----
    float m = fmaxf(fmaxf(sc[t], sc[t + 256]), fmaxf(sc[t + 512], sc[t + 768]));
    red[t] = m;
    __syncthreads();
    #pragma unroll
    for (int off = 128; off > 0; off >>= 1) {
        if (t < off) red[t] = fmaxf(red[t], red[t + off]);
        __syncthreads();
    }
    const float maxv = red[0];
    __syncthreads();

    // ---- exp + sum-reduce (each thread owns the same 4 slots it wrote) ----
    float ssum = 0.f;
    #pragma unroll
    for (int i = 0; i < 4; ++i) {
        const int kk = t + i * 256;
        const float e = __expf(sc[kk] - maxv);
        sc[kk] = e;
        ssum += e;
    }
    red[t] = ssum;
    __syncthreads();
    #pragma unroll
    for (int off = 128; off > 0; off >>= 1) {
        if (t < off) red[t] += red[t + off];
        __syncthreads();
    }
    const float inv = 1.f / red[0];
    __syncthreads();

    // ---- PV: thread (h, d4) accumulates float4 over its 128-k chunk ----
    const int d4 = t & 31;            // float4 column index
    const int h = t >> 5;             // k-chunk 0..7 (128 k each)
    float4 acc = make_float4(0.f, 0.f, 0.f, 0.f);
    const float4* vp = (const float4*)(Vb + h * 128 * DD) + d4;
    const float* wp = &sc[h * 128];
    #pragma unroll 4
    for (int kk = 0; kk < 128; ++kk) {
        const float w = wp[kk];                       // LDS broadcast
        const float4 v = vp[kk * (DD / 4)];           // coalesced 512B/32 lanes
        acc.x += w * v.x;
        acc.y += w * v.y;
        acc.z += w * v.z;
        acc.w += w * v.w;
    }
    pvs[h][4 * d4 + 0] = acc.x;
    pvs[h][4 * d4 + 1] = acc.y;
    pvs[h][4 * d4 + 2] = acc.z;
    pvs[h][4 * d4 + 3] = acc.w;
    __syncthreads();

    if (t < DD) {
        float s = 0.f;
        #pragma unroll
        for (int h2 = 0; h2 < 8; ++h2) s += pvs[h2][t];
        out[rowid * DD + t] = s * inv;
    }
}

extern "C" void kernel_launch(void* const* d_in, const int* in_sizes, int n_in,
                              void* d_out, int out_size, void* d_ws, size_t ws_size,
                              hipStream_t stream) {
    const float* x  = (const float*)d_in[0];
    const float* Wq = (const float*)d_in[1];
    const float* bq = (const float*)d_in[2];
    const float* Wk = (const float*)d_in[3];
    const float* bk = (const float*)d_in[4];
    const float* Wv = (const float*)d_in[5];
    const float* bv = (const float*)d_in[6];
    const int* causal = (const int*)d_in[7];
    float* out = (float*)d_out;

    const int rows = BB * SS;                 // 2048
    float* Qbuf = (float*)d_ws;               // rows*DD floats
    float* Kbuf = Qbuf + rows * DD;
    float* Vbuf = Kbuf + rows * DD;

    qkv_kernel<<<rows, DD, 0, stream>>>(x, Wq, bq, Wk, bk, Wv, bv,
                                        Qbuf, Kbuf, Vbuf);
    attn_kernel<<<rows, 256, 0, stream>>>(Qbuf, Kbuf, Vbuf, causal, out);
}

// Round 3
// 175.295 us; speedup vs baseline: 1.3212x; 1.3212x over previous
//
#include <hip/hip_runtime.h>
#include <math.h>

// Problem constants (from reference setup_inputs): B=2, S=1024, D=128
#define BB 2
#define SS 1024
#define DD 128
#define TQ 8      // query rows per attention block
#define TK 64     // k rows per LDS tile

// ---------------------------------------------------------------------------
// Kernel A: fused QKV projection. 8 rows per block, 384 threads.
// Thread (p, f) = (proj 0..2, feature 0..127) streams W_p row f from L2
// (float4) and reuses it across the 8 x-rows staged in LDS (broadcast reads).
// p is uniform per wave (128 | 64) -> no divergence.
// ---------------------------------------------------------------------------
__global__ __launch_bounds__(384) void qkv_kernel(
    const float* __restrict__ x,
    const float* __restrict__ Wq, const float* __restrict__ bq,
    const float* __restrict__ Wk, const float* __restrict__ bk,
    const float* __restrict__ Wv, const float* __restrict__ bv,
    float* __restrict__ Qo, float* __restrict__ Ko, float* __restrict__ Vo)
{
    __shared__ float xs[TQ * DD];
    const int row0 = blockIdx.x * TQ;       // flat row b*S+s
    const int t = threadIdx.x;

    if (t < TQ * DD / 4)
        ((float4*)xs)[t] = ((const float4*)(x + row0 * DD))[t];
    __syncthreads();

    const int p = t >> 7;                   // 0=Q 1=K 2=V
    const int f = t & 127;
    const float* W    = (p == 0) ? Wq : (p == 1) ? Wk : Wv;
    const float* bias = (p == 0) ? bq : (p == 1) ? bk : bv;
    float* Out        = (p == 0) ? Qo : (p == 1) ? Ko : Vo;

    float acc[TQ];
    #pragma unroll
    for (int r = 0; r < TQ; ++r) acc[r] = 0.f;

    const float4* w4 = (const float4*)(W + f * DD);
    const float4* xs4 = (const float4*)xs;
    #pragma unroll 4
    for (int d4 = 0; d4 < DD / 4; ++d4) {
        const float4 w = w4[d4];
        #pragma unroll
        for (int r = 0; r < TQ; ++r) {
            const float4 xv = xs4[r * 32 + d4];
            acc[r] += w.x * xv.x + w.y * xv.y + w.z * xv.z + w.w * xv.w;
        }
    }
    const float bb_ = bias[f];
    #pragma unroll
    for (int r = 0; r < TQ; ++r) {
        float v = acc[r] + bb_;
        if (p < 2) v = 1.f / (1.f + __expf(-v));   // sigmoid for Q,K
        Out[(row0 + r) * DD + f] = v;
    }
}

// ---------------------------------------------------------------------------
// Kernel B: q-tiled Lukasiewicz attention. One block = 8 q rows of one batch.
//   truth[q,k] = 1 - mean_d relu(Q[q,d]-K[k,d]); masked (causal, k>q) -> 0.
//   weights = softmax(truth*10) over ALL 1024 k (masked entries participate
//   with score 0); out = weights @ V.
// Phases: zero sc -> tile loop {prefetch K tile to regs, ds_write, scores}
//         -> per-row softmax -> PV (V from global, scores from LDS)
//         -> cross-chunk reduce through reused Ks buffer.
// ---------------------------------------------------------------------------
__global__ __launch_bounds__(256, 2) void attn_kernel(
    const float* __restrict__ Q, const float* __restrict__ K,
    const float* __restrict__ V, const int* __restrict__ causal_flag,
    float* __restrict__ out)
{
    __shared__ float Qs[TQ * DD];        // 4 KB
    __shared__ float Ks[TK * DD];        // 32 KB (reused as PV scratch)
    __shared__ float sc[TQ * SS];        // 32 KB scores -> exp weights
    __shared__ float sinv[TQ];

    const int blk = blockIdx.x;          // b*128 + qgroup
    const int b  = blk >> 7;
    const int q0 = (blk & 127) * TQ;
    const int t  = threadIdx.x;
    const bool causal = (causal_flag[0] != 0);

    const float* Kb = K + b * SS * DD;
    const float* Vb = V + b * SS * DD;

    // ---- zero score matrix (masked entries must read 0.0) ----
    #pragma unroll
    for (int i = 0; i < TQ * SS / 4 / 256; ++i)
        ((float4*)sc)[t + 256 * i] = make_float4(0.f, 0.f, 0.f, 0.f);

    // ---- stage Q tile ----
    if (t < TQ * DD / 4)
        ((float4*)Qs)[t] = ((const float4*)(Q + (b * SS + q0) * DD))[t];

    const int q  = t >> 5;               // 0..7  (row within tile)
    const int kk = t & 31;               // k-slot within K tile
    const int qrow = q0 + q;             // global q row
    const int ntiles = causal ? ((q0 + TQ - 1) >> 6) + 1 : (SS / TK);

    // ---- prefetch tile 0 into regs ----
    float4 rg[8];
    {
        const float4* src = (const float4*)(Kb) + 0;
        #pragma unroll
        for (int i = 0; i < 8; ++i) rg[i] = src[i * 256 + t];
    }

    const float4* Qs4 = (const float4*)Qs;
    const float4* Ks4 = (const float4*)Ks;

    for (int kt = 0; kt < ntiles; ++kt) {
        __syncthreads();                 // LDS tile free (prev scores done)
        #pragma unroll
        for (int i = 0; i < 8; ++i) ((float4*)Ks)[i * 256 + t] = rg[i];
        if (kt + 1 < ntiles) {           // prefetch next tile (overlaps scores)
            const float4* src = (const float4*)(Kb + (kt + 1) * TK * DD);
            #pragma unroll
            for (int i = 0; i < 8; ++i) rg[i] = src[i * 256 + t];
        }
        __syncthreads();                 // K tile visible

        const int ka = kt * TK + kk;     // this thread's two k rows
        const int kb_ = ka + 32;
        const bool doA = !causal || (ka  <= qrow);
        const bool doB = !causal || (kb_ <= qrow);
        if (doA || doB) {
            float aA0 = 0.f, aA1 = 0.f, aA2 = 0.f, aA3 = 0.f;
            float aB0 = 0.f, aB1 = 0.f, aB2 = 0.f, aB3 = 0.f;
            #pragma unroll
            for (int j = 0; j < 32; ++j) {
                const int d4 = (kk + j) & 31;         // rotation: conflict-free
                const float4 qv = Qs4[q * 32 + d4];
                const float4 va = Ks4[kk * 32 + d4];
                const float4 vb = Ks4[(kk + 32) * 32 + d4];
                aA0 += fmaxf(qv.x - va.x, 0.f);
                aA1 += fmaxf(qv.y - va.y, 0.f);
                aA2 += fmaxf(qv.z - va.z, 0.f);
                aA3 += fmaxf(qv.w - va.w, 0.f);
                aB0 += fmaxf(qv.x - vb.x, 0.f);
                aB1 += fmaxf(qv.y - vb.y, 0.f);
                aB2 += fmaxf(qv.z - vb.z, 0.f);
                aB3 += fmaxf(qv.w - vb.w, 0.f);
            }
            if (doA) sc[q * SS + ka]  = (1.f - (aA0 + aA1 + aA2 + aA3) * (1.f / DD)) * 10.f;
            if (doB) sc[q * SS + kb_] = (1.f - (aB0 + aB1 + aB2 + aB3) * (1.f / DD)) * 10.f;
        }
    }
    __syncthreads();                     // all scores written

    // ---- softmax over each q row (32 lanes per row) ----
    {
        float m = -1e30f;
        #pragma unroll
        for (int j = 0; j < 32; ++j) m = fmaxf(m, sc[q * SS + kk + 32 * j]);
        #pragma unroll
        for (int o = 16; o > 0; o >>= 1) m = fmaxf(m, __shfl_xor(m, o));
        float s = 0.f;
        #pragma unroll
        for (int j = 0; j < 32; ++j) {
            const int idx = q * SS + kk + 32 * j;
            const float e = __expf(sc[idx] - m);
            sc[idx] = e;
            s += e;
        }
        #pragma unroll
        for (int o = 16; o > 0; o >>= 1) s += __shfl_xor(s, o);
        if (kk == 0) sinv[q] = 1.f / s;
    }
    __syncthreads();                     // exp weights + sinv visible

    // ---- PV: thread (kc,d4) accumulates all 8 q rows over its 128-k chunk.
    //      V row read once per block (wave: 2 k-rows x 512B = 1KB unique). ----
    const int kc = t >> 5;
    const int d4 = t & 31;
    float4 acc[TQ];
    #pragma unroll
    for (int qi = 0; qi < TQ; ++qi) acc[qi] = make_float4(0.f, 0.f, 0.f, 0.f);

    const float4* vcol = (const float4*)Vb + d4;     // V[k][d4] at k*32
    const int kbase = kc * 128;
    #pragma unroll 4
    for (int k4 = 0; k4 < 128; k4 += 4) {
        const int kg = kbase + k4;
        const float4 v0 = vcol[(kg + 0) * 32];
        const float4 v1 = vcol[(kg + 1) * 32];
        const float4 v2 = vcol[(kg + 2) * 32];
        const float4 v3 = vcol[(kg + 3) * 32];
        #pragma unroll
        for (int qi = 0; qi < TQ; ++qi) {
            const float4 wv = *(const float4*)&sc[qi * SS + kg];
            acc[qi].x += wv.x * v0.x + wv.y * v1.x + wv.z * v2.x + wv.w * v3.x;
            acc[qi].y += wv.x * v0.y + wv.y * v1.y + wv.z * v2.y + wv.w * v3.y;
            acc[qi].z += wv.x * v0.z + wv.y * v1.z + wv.z * v2.z + wv.w * v3.z;
            acc[qi].w += wv.x * v0.w + wv.y * v1.w + wv.z * v2.w + wv.w * v3.w;
        }
    }

    // ---- cross-chunk reduce through reused Ks buffer ----
    float4* pvs = (float4*)Ks;           // [kc][q][d4] float4 = exactly 32 KB
    #pragma unroll
    for (int qi = 0; qi < TQ; ++qi)
        pvs[(kc * TQ + qi) * 32 + d4] = acc[qi];
    __syncthreads();

    {
        const int oq = t >> 5;           // output row 0..7
        const int od = t & 31;           // float4 column
        float4 s = make_float4(0.f, 0.f, 0.f, 0.f);
        #pragma unroll
        for (int c = 0; c < 8; ++c) {
            const float4 p = pvs[(c * TQ + oq) * 32 + od];
            s.x += p.x; s.y += p.y; s.z += p.z; s.w += p.w;
        }
        const float inv = sinv[oq];
        s.x *= inv; s.y *= inv; s.z *= inv; s.w *= inv;
        ((float4*)(out + (b * SS + q0 + oq) * DD))[od] = s;
    }
}

extern "C" void kernel_launch(void* const* d_in, const int* in_sizes, int n_in,
                              void* d_out, int out_size, void* d_ws, size_t ws_size,
                              hipStream_t stream) {
    const float* x  = (const float*)d_in[0];
    const float* Wq = (const float*)d_in[1];
    const float* bq = (const float*)d_in[2];
    const float* Wk = (const float*)d_in[3];
    const float* bk = (const float*)d_in[4];
    const float* Wv = (const float*)d_in[5];
    const float* bv = (const float*)d_in[6];
    const int* causal = (const int*)d_in[7];
    float* out = (float*)d_out;

    const int rows = BB * SS;                 // 2048
    float* Qbuf = (float*)d_ws;               // rows*DD floats each
    float* Kbuf = Qbuf + rows * DD;
    float* Vbuf = Kbuf + rows * DD;

    qkv_kernel<<<rows / TQ, 384, 0, stream>>>(x, Wq, bq, Wk, bk, Wv, bv,
                                              Qbuf, Kbuf, Vbuf);
    attn_kernel<<<BB * (SS / TQ), 256, 0, stream>>>(Qbuf, Kbuf, Vbuf, causal, out);
}

// Round 5
// 144.882 us; speedup vs baseline: 1.5985x; 1.2099x over previous
//
#include <hip/hip_runtime.h>
#include <math.h>

// Problem constants (from reference setup_inputs): B=2, S=1024, D=128
#define BB 2
#define SS 1024
#define DD 128

typedef _Float16 v2h __attribute__((ext_vector_type(2)));
typedef _Float16 h16;

// acc += sum_i relu(q_i - k_i) over 8 f16 elements (4 packed pairs).
__device__ __forceinline__ float acc8(float acc, v2h q0, v2h q1,
                                      v2h q2, v2h q3, float4 k)
{
    union { float4 f; v2h h[4]; } u; u.f = k;
    const v2h z = {(h16)0.0f, (h16)0.0f};
#if __has_builtin(__builtin_amdgcn_fdot2)
    const v2h one = {(h16)1.0f, (h16)1.0f};
    acc = __builtin_amdgcn_fdot2(__builtin_elementwise_max(q0 - u.h[0], z), one, acc, false);
    acc = __builtin_amdgcn_fdot2(__builtin_elementwise_max(q1 - u.h[1], z), one, acc, false);
    acc = __builtin_amdgcn_fdot2(__builtin_elementwise_max(q2 - u.h[2], z), one, acc, false);
    acc = __builtin_amdgcn_fdot2(__builtin_elementwise_max(q3 - u.h[3], z), one, acc, false);
#else
    v2h d0 = __builtin_elementwise_max(q0 - u.h[0], z);
    v2h d1 = __builtin_elementwise_max(q1 - u.h[1], z);
    v2h d2 = __builtin_elementwise_max(q2 - u.h[2], z);
    v2h d3 = __builtin_elementwise_max(q3 - u.h[3], z);
    acc += (float)d0.x + (float)d0.y + (float)d1.x + (float)d1.y
         + (float)d2.x + (float)d2.y + (float)d3.x + (float)d3.y;
#endif
    return acc;
}

// ---------------------------------------------------------------------------
// Kernel A: fused QKV projection. 8 x-rows per block, 384 threads.
// W staged per 32-d chunk in LDS (48 KB) with 16B-slot XOR swizzle so the
// compute read (lane = output feature f, stride 128 B) is conflict-free.
// Reg-prefetch of the next chunk overlaps compute. Q,K stored f16; V f32.
// ---------------------------------------------------------------------------
__global__ __launch_bounds__(384) void qkv_kernel(
    const float* __restrict__ x,
    const float* __restrict__ Wq, const float* __restrict__ bq,
    const float* __restrict__ Wk, const float* __restrict__ bk,
    const float* __restrict__ Wv, const float* __restrict__ bv,
    h16* __restrict__ Qh, h16* __restrict__ Kh, float* __restrict__ Vo)
{
    __shared__ float4 Wlds[3 * 128 * 8];   // 48 KB: [p][f][slot ^ (f&7)]
    __shared__ float4 xlds[8 * 32];        // 4 KB:  [r][d4]

    const int row0 = blockIdx.x * 8;
    const int t = threadIdx.x;

    if (t < 256) xlds[t] = ((const float4*)(x + row0 * DD))[t];

    const int p = t >> 7;                  // 0=Q 1=K 2=V (wave-uniform)
    const int f = t & 127;

    float4 wr[8];
    #pragma unroll
    for (int i = 0; i < 8; ++i) {          // prefetch chunk 0
        const int m = t + 384 * i;
        const int pp = m >> 10, rem = m & 1023, fr = rem >> 3, c4 = rem & 7;
        const float* Wp = (pp == 0) ? Wq : (pp == 1) ? Wk : Wv;
        wr[i] = ((const float4*)Wp)[fr * 32 + c4];
    }

    float acc[8];
    #pragma unroll
    for (int r = 0; r < 8; ++r) acc[r] = 0.f;

    for (int dc = 0; dc < 4; ++dc) {
        __syncthreads();                   // Wlds free (prev compute done)
        #pragma unroll
        for (int i = 0; i < 8; ++i) {
            const int m = t + 384 * i;
            const int pp = m >> 10, rem = m & 1023, fr = rem >> 3, c4 = rem & 7;
            Wlds[pp * 1024 + fr * 8 + (c4 ^ (fr & 7))] = wr[i];
        }
        if (dc < 3) {                      // prefetch next chunk
            #pragma unroll
            for (int i = 0; i < 8; ++i) {
                const int m = t + 384 * i;
                const int pp = m >> 10, rem = m & 1023, fr = rem >> 3, c4 = rem & 7;
                const float* Wp = (pp == 0) ? Wq : (pp == 1) ? Wk : Wv;
                wr[i] = ((const float4*)Wp)[fr * 32 + (dc + 1) * 8 + c4];
            }
        }
        __syncthreads();                   // Wlds chunk visible
        #pragma unroll
        for (int c4 = 0; c4 < 8; ++c4) {
            const float4 w = Wlds[p * 1024 + f * 8 + (c4 ^ (f & 7))];
            #pragma unroll
            for (int r = 0; r < 8; ++r) {
                const float4 xv = xlds[r * 32 + dc * 8 + c4];   // broadcast
                acc[r] += w.x * xv.x + w.y * xv.y + w.z * xv.z + w.w * xv.w;
            }
        }
    }

    const float bb_ = ((p == 0) ? bq : (p == 1) ? bk : bv)[f];
    #pragma unroll
    for (int r = 0; r < 8; ++r) {
        const float vv = acc[r] + bb_;
        if (p == 0)      Qh[(row0 + r) * DD + f] = (h16)(1.f / (1.f + __expf(-vv)));
        else if (p == 1) Kh[(row0 + r) * DD + f] = (h16)(1.f / (1.f + __expf(-vv)));
        else             Vo[(row0 + r) * DD + f] = vv;
    }
}

// ---------------------------------------------------------------------------
// Kernel S: Lukasiewicz scores + masked-to-0 softmax -> normalized weights.
// Block = 4 q rows (one per wave), 256 threads, grid 512 (2 blocks/CU).
// Q-row in registers (f16). K-tile 128 rows f16 in LDS, 16B-slot XOR swizzle.
// Thread (q=wave, kk=lane) owns k rows {kk, kk+64} per tile.
// Causal: batch-1 q-groups reversed for load balance.
// ---------------------------------------------------------------------------
__global__ __launch_bounds__(256, 2) void score_kernel(
    const h16* __restrict__ Qh, const h16* __restrict__ Kh,
    const int* __restrict__ causal_flag, h16* __restrict__ w)
{
    __shared__ float4 Ks4[128 * 16];       // 32 KB f16 K tile (swizzled)
    __shared__ float sc[4 * SS];           // 16 KB scores

    const int blk = blockIdx.x;
    const int b = blk >> 8;
    const int qgr = blk & 255;
    const int qg = b ? (255 - qgr) : qgr;  // reverse batch 1: balance causal work
    const int q0 = qg * 4;
    const int t = threadIdx.x;
    const int q = t >> 6;                  // wave id = q row in tile
    const int kk = t & 63;                 // lane id
    const bool causal = (causal_flag[0] != 0);
    const int qrow = q0 + q;
    const int ntiles = causal ? ((q0 + 4 + 127) >> 7) : (SS / 128);

    #pragma unroll
    for (int i = 0; i < 4; ++i)            // zero (masked entries read 0.0)
        ((float4*)sc)[t + 256 * i] = make_float4(0.f, 0.f, 0.f, 0.f);

    alignas(16) v2h qh[64];                // full q row, f16, in regs
    {
        const float4* qr = (const float4*)(Qh + (b * SS + qrow) * DD);
        #pragma unroll
        for (int i = 0; i < 16; ++i) ((float4*)qh)[i] = qr[i];  // broadcast
    }

    const float4* Ksrc = (const float4*)(Kh + b * SS * DD);
    float4 rg[8];
    #pragma unroll
    for (int i = 0; i < 8; ++i) rg[i] = Ksrc[t + 256 * i];   // prefetch tile 0

    const int km = kk & 7;
    for (int kt = 0; kt < ntiles; ++kt) {
        __syncthreads();                   // Ks free
        #pragma unroll
        for (int i = 0; i < 8; ++i) {
            const int n = t + 256 * i, r = n >> 4, s = n & 15;
            Ks4[(r << 4) + (s ^ (r & 7))] = rg[i];
        }
        if (kt + 1 < ntiles) {             // prefetch next (overlaps compute)
            const float4* src = Ksrc + (kt + 1) * 2048;
            #pragma unroll
            for (int i = 0; i < 8; ++i) rg[i] = src[t + 256 * i];
        }
        __syncthreads();                   // Ks visible

        float accA = 0.f, accB = 0.f;
        #pragma unroll
        for (int s = 0; s < 16; ++s) {     // 8 d-elements per step
            const float4 ka = Ks4[(kk << 4) + (s ^ km)];
            const float4 kb = Ks4[((kk + 64) << 4) + (s ^ km)];
            accA = acc8(accA, qh[s*4], qh[s*4+1], qh[s*4+2], qh[s*4+3], ka);
            accB = acc8(accB, qh[s*4], qh[s*4+1], qh[s*4+2], qh[s*4+3], kb);
        }
        const int ka_row = kt * 128 + kk, kb_row = ka_row + 64;
        if (!causal || ka_row <= qrow)
            sc[q * SS + ka_row] = (1.f - accA * (1.f / DD)) * 10.f;
        if (!causal || kb_row <= qrow)
            sc[q * SS + kb_row] = (1.f - accB * (1.f / DD)) * 10.f;
    }
    __syncthreads();

    // ---- softmax per wave over its q row (64 lanes x 16 elems) ----
    float mx = -1e30f;
    #pragma unroll
    for (int j = 0; j < 16; ++j) mx = fmaxf(mx, sc[q * SS + kk + 64 * j]);
    #pragma unroll
    for (int o = 32; o > 0; o >>= 1) mx = fmaxf(mx, __shfl_xor(mx, o));
    float ev[16];
    float sum = 0.f;
    #pragma unroll
    for (int j = 0; j < 16; ++j) {
        const float e = __expf(sc[q * SS + kk + 64 * j] - mx);
        ev[j] = e; sum += e;
    }
    #pragma unroll
    for (int o = 32; o > 0; o >>= 1) sum += __shfl_xor(sum, o);
    const float inv = 1.f / sum;

    h16* wrow = w + (b * SS + qrow) * SS;
    #pragma unroll
    for (int j = 0; j < 16; ++j) wrow[kk + 64 * j] = (h16)(ev[j] * inv);
}

// ---------------------------------------------------------------------------
// Kernel PV: out = weights @ V. Block = 4 q rows, 256 threads, grid 512.
// Weights tile staged in LDS (broadcast reads); V streamed from L2 coalesced
// (each V row read once per block, reused by 4 q rows). Cross-chunk reduce
// through LDS.
// ---------------------------------------------------------------------------
__global__ __launch_bounds__(256, 2) void pv_kernel(
    const h16* __restrict__ w, const float* __restrict__ V,
    float* __restrict__ out)
{
    __shared__ v2h wl[4 * 512];            // 8 KB: 4 rows x 1024 f16 weights
    __shared__ float4 pvs[8 * 4 * 32];     // 16 KB partials

    const int blk = blockIdx.x;
    const int b = blk >> 8, qg = blk & 255, q0 = qg * 4;
    const int t = threadIdx.x;

    const float4* wsrc = (const float4*)(w + (b * SS + q0) * SS);
    #pragma unroll
    for (int i = 0; i < 2; ++i) ((float4*)wl)[t + 256 * i] = wsrc[t + 256 * i];
    __syncthreads();

    const int kc = t >> 5;                 // k chunk (128 k each)
    const int d4 = t & 31;                 // float4 column
    const float4* vcol = (const float4*)(V + b * SS * DD) + d4;

    float4 acc[4];
    #pragma unroll
    for (int qi = 0; qi < 4; ++qi) acc[qi] = make_float4(0.f, 0.f, 0.f, 0.f);

    const int kbase = kc * 128;
    #pragma unroll 2
    for (int s = 0; s < 32; ++s) {
        const int k = kbase + s * 4;
        const float4 v0 = vcol[(k + 0) * 32];
        const float4 v1 = vcol[(k + 1) * 32];
        const float4 v2 = vcol[(k + 2) * 32];
        const float4 v3 = vcol[(k + 3) * 32];
        #pragma unroll
        for (int qi = 0; qi < 4; ++qi) {
            const v2h wa = wl[qi * 512 + (k >> 1)];             // broadcast
            const v2h wb = wl[qi * 512 + (k >> 1) + 1];
            const float fa0 = (float)wa.x, fa1 = (float)wa.y;
            const float fb0 = (float)wb.x, fb1 = (float)wb.y;
            acc[qi].x += fa0 * v0.x + fa1 * v1.x + fb0 * v2.x + fb1 * v3.x;
            acc[qi].y += fa0 * v0.y + fa1 * v1.y + fb0 * v2.y + fb1 * v3.y;
            acc[qi].z += fa0 * v0.z + fa1 * v1.z + fb0 * v2.z + fb1 * v3.z;
            acc[qi].w += fa0 * v0.w + fa1 * v1.w + fb0 * v2.w + fb1 * v3.w;
        }
    }

    #pragma unroll
    for (int qi = 0; qi < 4; ++qi) pvs[(kc * 4 + qi) * 32 + d4] = acc[qi];
    __syncthreads();

    if (t < 128) {
        const int oq = t >> 5, od = t & 31;
        float4 s = make_float4(0.f, 0.f, 0.f, 0.f);
        #pragma unroll
        for (int c = 0; c < 8; ++c) {
            const float4 p = pvs[(c * 4 + oq) * 32 + od];
            s.x += p.x; s.y += p.y; s.z += p.z; s.w += p.w;
        }
        ((float4*)(out + (b * SS + q0 + oq) * DD))[od] = s;
    }
}

extern "C" void kernel_launch(void* const* d_in, const int* in_sizes, int n_in,
                              void* d_out, int out_size, void* d_ws, size_t ws_size,
                              hipStream_t stream) {
    const float* x  = (const float*)d_in[0];
    const float* Wq = (const float*)d_in[1];
    const float* bq = (const float*)d_in[2];
    const float* Wk = (const float*)d_in[3];
    const float* bk = (const float*)d_in[4];
    const float* Wv = (const float*)d_in[5];
    const float* bv = (const float*)d_in[6];
    const int* causal = (const int*)d_in[7];
    float* out = (float*)d_out;

    const int rows = BB * SS;                     // 2048
    h16* Qh = (h16*)d_ws;                         // 512 KB
    h16* Kh = Qh + rows * DD;                     // 512 KB
    float* Vb = (float*)(Kh + rows * DD);         // 1 MB
    h16* wb = (h16*)(Vb + rows * DD);             // 4 MB (normalized weights)

    qkv_kernel<<<rows / 8, 384, 0, stream>>>(x, Wq, bq, Wk, bk, Wv, bv,
                                             Qh, Kh, Vb);
    score_kernel<<<BB * 256, 256, 0, stream>>>(Qh, Kh, causal, wb);
    pv_kernel<<<BB * 256, 256, 0, stream>>>(wb, Vb, out);
}

// Round 6
// 132.237 us; speedup vs baseline: 1.7514x; 1.0956x over previous
//
#include <hip/hip_runtime.h>
#include <math.h>

// Problem constants (from reference setup_inputs): B=2, S=1024, D=128
#define BB 2
#define SS 1024
#define DD 128

typedef _Float16 v2h __attribute__((ext_vector_type(2)));
typedef _Float16 h16;

// acc += sum_i relu(q_i - k_i) over 8 f16 elements (packed pairs + fdot2).
__device__ __forceinline__ float acc8(float acc, float4 qf, float4 kf)
{
    union U { float4 f; v2h h[4]; };
    U uq; uq.f = qf;
    U uk; uk.f = kf;
    const v2h z = {(h16)0.0f, (h16)0.0f};
#if __has_builtin(__builtin_amdgcn_fdot2)
    const v2h one = {(h16)1.0f, (h16)1.0f};
    #pragma unroll
    for (int i = 0; i < 4; ++i)
        acc = __builtin_amdgcn_fdot2(
            __builtin_elementwise_max(uq.h[i] - uk.h[i], z), one, acc, false);
#else
    #pragma unroll
    for (int i = 0; i < 4; ++i) {
        v2h d = __builtin_elementwise_max(uq.h[i] - uk.h[i], z);
        acc += (float)d.x + (float)d.y;
    }
#endif
    return acc;
}

// ---------------------------------------------------------------------------
// Kernel A: fused QKV projection. 8 x-rows per block, 384 threads.
// W staged per 32-d chunk in LDS (48 KB) with 16B-slot XOR swizzle so the
// compute read (lane = output feature f, stride 128 B) is conflict-free.
// Reg-prefetch of the next chunk overlaps compute. Q,K stored f16; V f32.
// ---------------------------------------------------------------------------
__global__ __launch_bounds__(384) void qkv_kernel(
    const float* __restrict__ x,
    const float* __restrict__ Wq, const float* __restrict__ bq,
    const float* __restrict__ Wk, const float* __restrict__ bk,
    const float* __restrict__ Wv, const float* __restrict__ bv,
    h16* __restrict__ Qh, h16* __restrict__ Kh, float* __restrict__ Vo)
{
    __shared__ float4 Wlds[3 * 128 * 8];   // 48 KB: [p][f][slot ^ (f&7)]
    __shared__ float4 xlds[8 * 32];        // 4 KB:  [r][d4]

    const int row0 = blockIdx.x * 8;
    const int t = threadIdx.x;

    if (t < 256) xlds[t] = ((const float4*)(x + row0 * DD))[t];

    const int p = t >> 7;                  // 0=Q 1=K 2=V (wave-uniform)
    const int f = t & 127;

    float4 wr[8];
    #pragma unroll
    for (int i = 0; i < 8; ++i) {          // prefetch chunk 0
        const int m = t + 384 * i;
        const int pp = m >> 10, rem = m & 1023, fr = rem >> 3, c4 = rem & 7;
        const float* Wp = (pp == 0) ? Wq : (pp == 1) ? Wk : Wv;
        wr[i] = ((const float4*)Wp)[fr * 32 + c4];
    }

    float acc[8];
    #pragma unroll
    for (int r = 0; r < 8; ++r) acc[r] = 0.f;

    for (int dc = 0; dc < 4; ++dc) {
        __syncthreads();                   // Wlds free (prev compute done)
        #pragma unroll
        for (int i = 0; i < 8; ++i) {
            const int m = t + 384 * i;
            const int pp = m >> 10, rem = m & 1023, fr = rem >> 3, c4 = rem & 7;
            Wlds[pp * 1024 + fr * 8 + (c4 ^ (fr & 7))] = wr[i];
        }
        if (dc < 3) {                      // prefetch next chunk
            #pragma unroll
            for (int i = 0; i < 8; ++i) {
                const int m = t + 384 * i;
                const int pp = m >> 10, rem = m & 1023, fr = rem >> 3, c4 = rem & 7;
                const float* Wp = (pp == 0) ? Wq : (pp == 1) ? Wk : Wv;
                wr[i] = ((const float4*)Wp)[fr * 32 + (dc + 1) * 8 + c4];
            }
        }
        __syncthreads();                   // Wlds chunk visible
        #pragma unroll
        for (int c4 = 0; c4 < 8; ++c4) {
            const float4 w = Wlds[p * 1024 + f * 8 + (c4 ^ (f & 7))];
            #pragma unroll
            for (int r = 0; r < 8; ++r) {
                const float4 xv = xlds[r * 32 + dc * 8 + c4];   // broadcast
                acc[r] += w.x * xv.x + w.y * xv.y + w.z * xv.z + w.w * xv.w;
            }
        }
    }

    const float bb_ = ((p == 0) ? bq : (p == 1) ? bk : bv)[f];
    #pragma unroll
    for (int r = 0; r < 8; ++r) {
        const float vv = acc[r] + bb_;
        if (p == 0)      Qh[(row0 + r) * DD + f] = (h16)(1.f / (1.f + __expf(-vv)));
        else if (p == 1) Kh[(row0 + r) * DD + f] = (h16)(1.f / (1.f + __expf(-vv)));
        else             Vo[(row0 + r) * DD + f] = vv;
    }
}

// ---------------------------------------------------------------------------
// Kernel B (fused): Lukasiewicz scores + masked-to-0 softmax + PV.
// Block = 4 q rows (one wave each), 256 threads, grid 512 (2 blocks/CU).
// Q rows in LDS (broadcast reads — keeps VGPRs ~85, no spill at the
// launch_bounds(256,2) 128-VGPR cap). K-tile 128 rows f16 in LDS with 16B-slot
// XOR swizzle. Weights normalized IN PLACE in LDS (f32) then PV streams V
// from L2; partials reduce through the reused K-tile buffer.
// Causal: batch-1 q-groups reversed so heavy+light blocks pair per CU.
// Masked entries keep score 0.0 and participate in softmax (ref semantics).
// ---------------------------------------------------------------------------
__global__ __launch_bounds__(256, 2) void attn_kernel(
    const h16* __restrict__ Qh, const h16* __restrict__ Kh,
    const float* __restrict__ V, const int* __restrict__ causal_flag,
    float* __restrict__ out)
{
    __shared__ float4 Ks4[128 * 16];             // 32 KB K tile; reused as pvs
    __shared__ __align__(16) float sc[4 * SS];   // 16 KB scores -> weights
    __shared__ float4 qls[4 * 16];               // 1 KB Q tile (f16 pairs)

    const int blk = blockIdx.x;
    const int b = blk >> 8;
    const int qgr = blk & 255;
    const int qg = b ? (255 - qgr) : qgr;  // reverse batch 1: balance causal
    const int q0 = qg * 4;
    const int t = threadIdx.x;
    const int q = t >> 6;                  // wave id = q row in tile
    const int kk = t & 63;                 // lane id
    const bool causal = (causal_flag[0] != 0);
    const int qrow = q0 + q;
    const int ntiles = causal ? ((q0 + 4 + 127) >> 7) : (SS / 128);

    #pragma unroll
    for (int i = 0; i < 4; ++i)            // zero (masked entries read 0.0)
        ((float4*)sc)[t + 256 * i] = make_float4(0.f, 0.f, 0.f, 0.f);

    if (t < 64) qls[t] = ((const float4*)(Qh + (b * SS + q0) * DD))[t];

    const float4* Ksrc = (const float4*)(Kh + b * SS * DD);
    float4 rg[8];
    #pragma unroll
    for (int i = 0; i < 8; ++i) rg[i] = Ksrc[t + 256 * i];   // prefetch tile 0

    const int km = kk & 7;
    for (int kt = 0; kt < ntiles; ++kt) {
        __syncthreads();                   // Ks free (incl. qls/sc ready, kt=0)
        #pragma unroll
        for (int i = 0; i < 8; ++i) {
            const int n = t + 256 * i, r = n >> 4, s = n & 15;
            Ks4[(r << 4) + (s ^ (r & 7))] = rg[i];
        }
        if (kt + 1 < ntiles) {             // prefetch next (overlaps compute)
            const float4* src = Ksrc + (kt + 1) * 2048;
            #pragma unroll
            for (int i = 0; i < 8; ++i) rg[i] = src[t + 256 * i];
        }
        __syncthreads();                   // Ks visible

        float accA = 0.f, accB = 0.f;
        #pragma unroll
        for (int s = 0; s < 16; ++s) {     // 8 d-elements per step
            const float4 qv = qls[q * 16 + s];                  // broadcast
            const float4 ka = Ks4[(kk << 4) + (s ^ km)];
            const float4 kb = Ks4[((kk + 64) << 4) + (s ^ km)];
            accA = acc8(accA, qv, ka);
            accB = acc8(accB, qv, kb);
        }
        const int ka_row = kt * 128 + kk, kb_row = ka_row + 64;
        if (!causal || ka_row <= qrow)
            sc[q * SS + ka_row] = (1.f - accA * (1.f / DD)) * 10.f;
        if (!causal || kb_row <= qrow)
            sc[q * SS + kb_row] = (1.f - accB * (1.f / DD)) * 10.f;
    }
    __syncthreads();

    // ---- softmax per wave; normalized weights written back in place ----
    {
        float mx = -1e30f;
        #pragma unroll
        for (int j = 0; j < 16; ++j) mx = fmaxf(mx, sc[q * SS + kk + 64 * j]);
        #pragma unroll
        for (int o = 32; o > 0; o >>= 1) mx = fmaxf(mx, __shfl_xor(mx, o));
        float ev[16];
        float sum = 0.f;
        #pragma unroll
        for (int j = 0; j < 16; ++j) {
            ev[j] = __expf(sc[q * SS + kk + 64 * j] - mx);
            sum += ev[j];
        }
        #pragma unroll
        for (int o = 32; o > 0; o >>= 1) sum += __shfl_xor(sum, o);
        const float inv = 1.f / sum;
        #pragma unroll
        for (int j = 0; j < 16; ++j) sc[q * SS + kk + 64 * j] = ev[j] * inv;
    }
    __syncthreads();                       // weights visible

    // ---- PV: thread (kc,d4) accumulates 4 q rows over its 128-k chunk.
    //      V rows from L2 (coalesced, read once per block); weights via
    //      LDS broadcast. ----
    const int kc = t >> 5;
    const int d4 = t & 31;
    const float4* vcol = (const float4*)(V + b * SS * DD) + d4;

    float4 acc[4];
    #pragma unroll
    for (int qi = 0; qi < 4; ++qi) acc[qi] = make_float4(0.f, 0.f, 0.f, 0.f);

    const int kbase = kc * 128;
    #pragma unroll 2
    for (int s = 0; s < 32; ++s) {
        const int k = kbase + s * 4;
        const float4 v0 = vcol[(k + 0) * 32];
        const float4 v1 = vcol[(k + 1) * 32];
        const float4 v2 = vcol[(k + 2) * 32];
        const float4 v3 = vcol[(k + 3) * 32];
        #pragma unroll
        for (int qi = 0; qi < 4; ++qi) {
            const float4 wv = *(const float4*)&sc[qi * SS + k];  // broadcast
            acc[qi].x += wv.x * v0.x + wv.y * v1.x + wv.z * v2.x + wv.w * v3.x;
            acc[qi].y += wv.x * v0.y + wv.y * v1.y + wv.z * v2.y + wv.w * v3.y;
            acc[qi].z += wv.x * v0.z + wv.y * v1.z + wv.z * v2.z + wv.w * v3.z;
            acc[qi].w += wv.x * v0.w + wv.y * v1.w + wv.z * v2.w + wv.w * v3.w;
        }
    }

    // ---- cross-chunk reduce through reused Ks4 buffer ----
    float4* pvs = (float4*)Ks4;            // [kc][qi][d4] = 16 KB
    #pragma unroll
    for (int qi = 0; qi < 4; ++qi) pvs[(kc * 4 + qi) * 32 + d4] = acc[qi];
    __syncthreads();

    if (t < 128) {
        const int oq = t >> 5, od = t & 31;
        float4 s = make_float4(0.f, 0.f, 0.f, 0.f);
        #pragma unroll
        for (int c = 0; c < 8; ++c) {
            const float4 p = pvs[(c * 4 + oq) * 32 + od];
            s.x += p.x; s.y += p.y; s.z += p.z; s.w += p.w;
        }
        ((float4*)(out + (b * SS + q0 + oq) * DD))[od] = s;
    }
}

extern "C" void kernel_launch(void* const* d_in, const int* in_sizes, int n_in,
                              void* d_out, int out_size, void* d_ws, size_t ws_size,
                              hipStream_t stream) {
    const float* x  = (const float*)d_in[0];
    const float* Wq = (const float*)d_in[1];
    const float* bq = (const float*)d_in[2];
    const float* Wk = (const float*)d_in[3];
    const float* bk = (const float*)d_in[4];
    const float* Wv = (const float*)d_in[5];
    const float* bv = (const float*)d_in[6];
    const int* causal = (const int*)d_in[7];
    float* out = (float*)d_out;

    const int rows = BB * SS;                     // 2048
    h16* Qh = (h16*)d_ws;                         // 512 KB
    h16* Kh = Qh + rows * DD;                     // 512 KB
    float* Vb = (float*)(Kh + rows * DD);         // 1 MB

    qkv_kernel<<<rows / 8, 384, 0, stream>>>(x, Wq, bq, Wk, bk, Wv, bv,
                                             Qh, Kh, Vb);
    attn_kernel<<<BB * 256, 256, 0, stream>>>(Qh, Kh, Vb, causal, out);
}

// Round 7
// 117.726 us; speedup vs baseline: 1.9672x; 1.1233x over previous
//
#include <hip/hip_runtime.h>
#include <math.h>

// Problem constants (from reference setup_inputs): B=2, S=1024, D=128
#define BB 2
#define SS 1024
#define DD 128

typedef _Float16 v2h __attribute__((ext_vector_type(2)));
typedef _Float16 h16;

// acc += sum_i relu(q_i - k_i) over 8 f16 elements (packed pairs + fdot2).
__device__ __forceinline__ float acc8(float acc, float4 qf, float4 kf)
{
    union U { float4 f; v2h h[4]; };
    U uq; uq.f = qf;
    U uk; uk.f = kf;
    const v2h z = {(h16)0.0f, (h16)0.0f};
#if __has_builtin(__builtin_amdgcn_fdot2)
    const v2h one = {(h16)1.0f, (h16)1.0f};
    #pragma unroll
    for (int i = 0; i < 4; ++i)
        acc = __builtin_amdgcn_fdot2(
            __builtin_elementwise_max(uq.h[i] - uk.h[i], z), one, acc, false);
#else
    #pragma unroll
    for (int i = 0; i < 4; ++i) {
        v2h d = __builtin_elementwise_max(uq.h[i] - uk.h[i], z);
        acc += (float)d.x + (float)d.y;
    }
#endif
    return acc;
}

// ---------------------------------------------------------------------------
// Kernel T: transpose the three 128x128 W matrices -> Wt[p][d][f].
// Grid 12 blocks (3 proj x 4 stripes of 32 f-rows), 256 threads.
// Padded LDS tile, coalesced global read and write.
// ---------------------------------------------------------------------------
__global__ __launch_bounds__(256) void wt_kernel(
    const float* __restrict__ Wq, const float* __restrict__ Wk,
    const float* __restrict__ Wv, float* __restrict__ Wt)
{
    __shared__ float lt[32 * 129];
    const int p = blockIdx.x >> 2;
    const int f0 = (blockIdx.x & 3) * 32;
    const float* W = (p == 0) ? Wq : (p == 1) ? Wk : Wv;
    const int t = threadIdx.x;

    #pragma unroll
    for (int i = 0; i < 16; ++i) {          // load stripe [32f][128d]
        const int n = i * 256 + t;
        const int fi = n >> 7, d = n & 127;
        lt[fi * 129 + d] = W[(f0 + fi) * 128 + d];
    }
    __syncthreads();
    #pragma unroll
    for (int i = 0; i < 16; ++i) {          // store [128d][32f]
        const int m = i * 256 + t;
        const int d = m >> 5, fo = m & 31;
        Wt[p * 16384 + d * 128 + f0 + fo] = lt[fo * 129 + d];
    }
}

// ---------------------------------------------------------------------------
// Kernel A: QKV projection using pre-transposed W (d-major).
// Grid 768 = 3 proj x 256 groups of 8 rows; 256 threads (f = t&127,
// h = t>>7 picks 4 rows). Inner loop: w = Wt[d*128+f] (coalesced 256B/wave,
// L1-resident: same 64KB reused by all 256 row-groups), x via LDS broadcast.
// No barriers in the main loop, 4KB LDS, ~35 VGPR -> high occupancy.
// Q,K stored f16 (sigmoid in (0,1)); V f32.
// ---------------------------------------------------------------------------
__global__ __launch_bounds__(256, 4) void qkv_kernel(
    const float* __restrict__ x, const float* __restrict__ Wt,
    const float* __restrict__ bq, const float* __restrict__ bk,
    const float* __restrict__ bv,
    h16* __restrict__ Qh, h16* __restrict__ Kh, float* __restrict__ Vo)
{
    __shared__ float xs[8 * 128];          // 4 KB
    const int b = blockIdx.x;
    const int p = b >> 8;                  // proj (block-uniform)
    const int row0 = (b & 255) * 8;
    const int t = threadIdx.x;
    const int f = t & 127;
    const int h = t >> 7;                  // row half: rows h*4 .. h*4+3

    ((float4*)xs)[t] = ((const float4*)(x + row0 * DD))[t];
    __syncthreads();

    const float* wt = Wt + p * 16384;
    float acc[4] = {0.f, 0.f, 0.f, 0.f};

    for (int d0 = 0; d0 < 128; d0 += 8) {
        float w[8];
        #pragma unroll
        for (int j = 0; j < 8; ++j) w[j] = wt[(d0 + j) * 128 + f];
        #pragma unroll
        for (int j = 0; j < 8; ++j) {
            #pragma unroll
            for (int r = 0; r < 4; ++r)
                acc[r] += w[j] * xs[(h * 4 + r) * 128 + d0 + j];  // broadcast
        }
    }

    const float bb_ = ((p == 0) ? bq : (p == 1) ? bk : bv)[f];
    #pragma unroll
    for (int r = 0; r < 4; ++r) {
        const int row = row0 + h * 4 + r;
        const float vv = acc[r] + bb_;
        if (p == 0)      Qh[row * DD + f] = (h16)(1.f / (1.f + __expf(-vv)));
        else if (p == 1) Kh[row * DD + f] = (h16)(1.f / (1.f + __expf(-vv)));
        else             Vo[row * DD + f] = vv;
    }
}

// ---------------------------------------------------------------------------
// Kernel B (fused): Lukasiewicz scores + masked-to-0 softmax + PV.
// Block = 4 q rows (one wave each), 256 threads, grid 512.
// K tiles of 64 rows f16 in LDS with PADDED stride (17 float4 per row ->
// bank = (17*kk+s)%32, conflict-free, no XOR). Pipeline reordered so the
// next-tile prefetch is issued AFTER the barrier and drains after compute
// (the compiler's vmcnt(0)-before-barrier then lands post-compute).
// Weights normalized in place in LDS (f32); PV streams V from L2.
// Causal: batch-1 q-groups reversed to pair heavy+light blocks per CU.
// Masked entries keep score 0.0 and participate in softmax (ref semantics).
// ---------------------------------------------------------------------------
__global__ __launch_bounds__(256, 4) void attn_kernel(
    const h16* __restrict__ Qh, const h16* __restrict__ Kh,
    const float* __restrict__ V, const int* __restrict__ causal_flag,
    float* __restrict__ out)
{
    __shared__ float4 Ks4[64 * 17];              // 17.4 KB (reused as pvs)
    __shared__ __align__(16) float sc[4 * SS];   // 16 KB scores -> weights
    __shared__ float4 qls[4 * 16];               // 1 KB Q tile (f16)

    const int blk = blockIdx.x;
    const int b = blk >> 8;
    const int qgr = blk & 255;
    const int qg = b ? (255 - qgr) : qgr;  // reverse batch 1: balance causal
    const int q0 = qg * 4;
    const int t = threadIdx.x;
    const int q = t >> 6;                  // wave id = q row in tile
    const int kk = t & 63;                 // lane id = k row within tile
    const bool causal = (causal_flag[0] != 0);
    const int qrow = q0 + q;
    const int ntiles = causal ? ((q0 + 67) >> 6) : (SS / 64);

    #pragma unroll
    for (int i = 0; i < 4; ++i)            // zero (masked entries read 0.0)
        ((float4*)sc)[t + 256 * i] = make_float4(0.f, 0.f, 0.f, 0.f);

    if (t < 64) qls[t] = ((const float4*)(Qh + (b * SS + q0) * DD))[t];

    const float4* Ksrc = (const float4*)(Kh + b * SS * DD);
    float4 rg[4];                          // one 64-row tile = 1024 float4
    #pragma unroll
    for (int i = 0; i < 4; ++i) rg[i] = Ksrc[i * 256 + t];   // tile 0

    for (int kt = 0; kt < ntiles; ++kt) {
        __syncthreads();                   // (A) Ks free; drains prev prefetch
                                           //     AFTER prev compute (covered)
        #pragma unroll
        for (int i = 0; i < 4; ++i) {
            const int n = i * 256 + t, r = n >> 4, s = n & 15;
            Ks4[r * 17 + s] = rg[i];
        }
        __syncthreads();                   // (B) Ks visible (no vmem pending)
        if (kt + 1 < ntiles) {             // issue next prefetch, wait later
            const float4* src = Ksrc + (kt + 1) * 1024;
            #pragma unroll
            for (int i = 0; i < 4; ++i) rg[i] = src[i * 256 + t];
        }

        float a = 0.f;                     // this lane's k row vs q row
        #pragma unroll
        for (int s = 0; s < 16; ++s)
            a = acc8(a, qls[q * 16 + s], Ks4[kk * 17 + s]);

        const int krow = kt * 64 + kk;
        if (!causal || krow <= qrow)
            sc[q * SS + krow] = (1.f - a * (1.f / DD)) * 10.f;
    }
    __syncthreads();

    // ---- softmax per wave; normalized weights written back in place ----
    {
        float mx = -1e30f;
        #pragma unroll
        for (int j = 0; j < 16; ++j) mx = fmaxf(mx, sc[q * SS + kk + 64 * j]);
        #pragma unroll
        for (int o = 32; o > 0; o >>= 1) mx = fmaxf(mx, __shfl_xor(mx, o));
        float ev[16];
        float sum = 0.f;
        #pragma unroll
        for (int j = 0; j < 16; ++j) {
            ev[j] = __expf(sc[q * SS + kk + 64 * j] - mx);
            sum += ev[j];
        }
        #pragma unroll
        for (int o = 32; o > 0; o >>= 1) sum += __shfl_xor(sum, o);
        const float inv = 1.f / sum;
        #pragma unroll
        for (int j = 0; j < 16; ++j) sc[q * SS + kk + 64 * j] = ev[j] * inv;
    }
    __syncthreads();                       // weights visible

    // ---- PV: thread (kc,d4) accumulates 4 q rows over its 128-k chunk.
    //      V rows from L2 (coalesced, read once per block); weights via
    //      LDS broadcast. ----
    const int kc = t >> 5;
    const int d4 = t & 31;
    const float4* vcol = (const float4*)(V + b * SS * DD) + d4;

    float4 acc[4];
    #pragma unroll
    for (int qi = 0; qi < 4; ++qi) acc[qi] = make_float4(0.f, 0.f, 0.f, 0.f);

    const int kbase = kc * 128;
    #pragma unroll 2
    for (int s = 0; s < 32; ++s) {
        const int k = kbase + s * 4;
        const float4 v0 = vcol[(k + 0) * 32];
        const float4 v1 = vcol[(k + 1) * 32];
        const float4 v2 = vcol[(k + 2) * 32];
        const float4 v3 = vcol[(k + 3) * 32];
        #pragma unroll
        for (int qi = 0; qi < 4; ++qi) {
            const float4 wv = *(const float4*)&sc[qi * SS + k];  // broadcast
            acc[qi].x += wv.x * v0.x + wv.y * v1.x + wv.z * v2.x + wv.w * v3.x;
            acc[qi].y += wv.x * v0.y + wv.y * v1.y + wv.z * v2.y + wv.w * v3.y;
            acc[qi].z += wv.x * v0.z + wv.y * v1.z + wv.z * v2.z + wv.w * v3.z;
            acc[qi].w += wv.x * v0.w + wv.y * v1.w + wv.z * v2.w + wv.w * v3.w;
        }
    }

    // ---- cross-chunk reduce through reused Ks4 buffer ----
    float4* pvs = (float4*)Ks4;            // [kc][qi][d4] = 16 KB <= 17.4 KB
    #pragma unroll
    for (int qi = 0; qi < 4; ++qi) pvs[(kc * 4 + qi) * 32 + d4] = acc[qi];
    __syncthreads();

    if (t < 128) {
        const int oq = t >> 5, od = t & 31;
        float4 s = make_float4(0.f, 0.f, 0.f, 0.f);
        #pragma unroll
        for (int c = 0; c < 8; ++c) {
            const float4 p = pvs[(c * 4 + oq) * 32 + od];
            s.x += p.x; s.y += p.y; s.z += p.z; s.w += p.w;
        }
        ((float4*)(out + (b * SS + q0 + oq) * DD))[od] = s;
    }
}

extern "C" void kernel_launch(void* const* d_in, const int* in_sizes, int n_in,
                              void* d_out, int out_size, void* d_ws, size_t ws_size,
                              hipStream_t stream) {
    const float* x  = (const float*)d_in[0];
    const float* Wq = (const float*)d_in[1];
    const float* bq = (const float*)d_in[2];
    const float* Wk = (const float*)d_in[3];
    const float* bk = (const float*)d_in[4];
    const float* Wv = (const float*)d_in[5];
    const float* bv = (const float*)d_in[6];
    const int* causal = (const int*)d_in[7];
    float* out = (float*)d_out;

    const int rows = BB * SS;                     // 2048
    float* Wt = (float*)d_ws;                     // 3*16384 f32 = 192 KB
    h16* Qh = (h16*)(Wt + 3 * 16384);             // 512 KB
    h16* Kh = Qh + rows * DD;                     // 512 KB
    float* Vb = (float*)(Kh + rows * DD);         // 1 MB

    wt_kernel<<<12, 256, 0, stream>>>(Wq, Wk, Wv, Wt);
    qkv_kernel<<<3 * 256, 256, 0, stream>>>(x, Wt, bq, bk, bv, Qh, Kh, Vb);
    attn_kernel<<<BB * 256, 256, 0, stream>>>(Qh, Kh, Vb, causal, out);
}